// Round 14
// baseline (237.352 us; speedup 1.0000x reference)
//
#include <hip/hip_runtime.h>
#include <hip/hip_bf16.h>
#include <math.h>

typedef __attribute__((ext_vector_type(8))) __bf16 bf16x8;
typedef __attribute__((ext_vector_type(4))) float f32x4;

#define DIM 1024
#define SEQ 2048
#define BATCH 4
#define ROWS (BATCH*SEQ)
#define NBX 16   // scores N-tiles per row

__device__ __forceinline__ unsigned short f2bf(float f) {
  unsigned int u = __float_as_uint(f);
  u += 0x7FFF + ((u >> 16) & 1);   // RNE
  return (unsigned short)(u >> 16);
}

__device__ __forceinline__ void gload_lds16(const void* g, void* lds) {
  __builtin_amdgcn_global_load_lds((__attribute__((address_space(1))) void*)g,
                                   (__attribute__((address_space(3))) void*)lds,
                                   16, 0, 0);
}

// ---------- f32 -> bf16 ----------
__global__ __launch_bounds__(256)
void conv_f32_bf16(const float* __restrict__ src, unsigned short* __restrict__ dst, int n8) {
  int i = blockIdx.x * blockDim.x + threadIdx.x;
  if (i >= n8) return;
  const float4* s = reinterpret_cast<const float4*>(src) + (size_t)i * 2;
  float4 a = s[0], b = s[1];
  union { unsigned short h[8]; uint4 v; } p;
  p.h[0]=f2bf(a.x); p.h[1]=f2bf(a.y); p.h[2]=f2bf(a.z); p.h[3]=f2bf(a.w);
  p.h[4]=f2bf(b.x); p.h[5]=f2bf(b.y); p.h[6]=f2bf(b.z); p.h[7]=f2bf(b.w);
  reinterpret_cast<uint4*>(dst)[i] = p.v;
}

// ---------- merged weight transpose: z=0..2 -> W_in col-chunks, z=3 -> W_out ----------
__global__ __launch_bounds__(1024)
void transpose_weights(const float* __restrict__ W_in, unsigned short* __restrict__ WinT,
                       const float* __restrict__ W_out, unsigned short* __restrict__ WoutT) {
  __shared__ unsigned short tile[32][33];
  const int z = blockIdx.z;
  const float* src; unsigned short* dst; int ldsrc, bx;
  if (z < 3) { src = W_in;  dst = WinT;  ldsrc = 3 * DIM; bx = z * 32 + blockIdx.x; }
  else       { src = W_out; dst = WoutT; ldsrc = DIM;     bx = blockIdx.x; }
  int tx = threadIdx.x, ty = threadIdx.y;
  int r = blockIdx.y * 32 + ty, c = bx * 32 + tx;
  tile[ty][tx] = f2bf(src[(size_t)r * ldsrc + c]);
  __syncthreads();
  dst[(size_t)(bx * 32 + ty) * DIM + blockIdx.y * 32 + tx] = tile[tx][ty];
}

// ---------- combine per-tile stats -> (rowmax, 1/rowsum) ----------
__global__ __launch_bounds__(256)
void stat_combine(const float2* __restrict__ pstat, float2* __restrict__ rowstat) {
  const int r = blockIdx.x * 256 + threadIdx.x;   // 0..SEQ-1
  const int z = blockIdx.y;
  float2 v[NBX];
  float M = -3.4e38f;
#pragma unroll
  for (int i = 0; i < NBX; ++i) {
    v[i] = pstat[((size_t)z * NBX + i) * SEQ + r];
    M = fmaxf(M, v[i].x);
  }
  float S = 0.f;
#pragma unroll
  for (int i = 0; i < NBX; ++i) S += v[i].y * __expf(v[i].x - M);
  rowstat[(size_t)z * SEQ + r] = make_float2(M, 1.f / S);
}

#define EPI_QKV 0
#define EPI_SC  1   // scores: f32 out + per-tile row stats
#define EPI_PVF 2   // fused-exp PV: A = raw S f32 + rowstat, bf16 out
#define EPI_BIAS_F32 3

// ---------- m97-archetype NT GEMM (r12-proven, 799 TF on QKV) ----------
// 128x128 tile, BK=64, 4 waves (2x2), 32 KB LDS single-buffer, 2 barriers/tile.
// XOR swizzle both-sides. EPI_QKV: M-fastest grid + V->Vt transposed epilogue.
// EPI_SC: stats epilogue (butterfly over fr + LDS-scratch wc-combine).
// EPI_PVF: A reg-staged as exp(S - M)*invS -> bf16 (write-side swizzle).
template<int EPI>
__global__ __launch_bounds__(256, 3)
void gemm97(const unsigned short* __restrict__ A, int lda, size_t sA,
            const unsigned short* __restrict__ B, int ldb, size_t sB,
            void* __restrict__ C, int ldc, size_t sC,
            const float* __restrict__ bias, int K,
            unsigned short* __restrict__ VtOut, size_t sVt,
            float2* __restrict__ pstat, const float2* __restrict__ rowstat) {
  __shared__ unsigned short As[128 * 64];
  __shared__ unsigned short Bs[128 * 64];

  const int tid = threadIdx.x;
  const int lane = tid & 63, wave = tid >> 6;
  const int wr = wave >> 1, wc = wave & 1;
  const int fr = lane & 15, fk = lane >> 4;
  const int tileM = (EPI == EPI_QKV ? blockIdx.x : blockIdx.y) * 128;
  const int tileN = (EPI == EPI_QKV ? blockIdx.y : blockIdx.x) * 128;
  const unsigned short* Ab = A + (size_t)blockIdx.z * sA;
  const unsigned short* Bb = B + (size_t)blockIdx.z * sB;

  const int srow = tid >> 3;                 // 0..31
  const int sg = (tid & 7) ^ (srow & 7);     // pre-swizzled source 16B-chunk
  const int sp = (tid & 7) * 8;              // linear LDS slot (shorts)

  // PVF: per-thread staging-row softmax stats (rows fixed across K-tiles)
  float mR[4], iR[4];
  if constexpr (EPI == EPI_PVF) {
#pragma unroll
    for (int q = 0; q < 4; ++q) {
      float2 st = rowstat[(size_t)blockIdx.z * SEQ + tileM + q * 32 + srow];
      mR[q] = st.x; iR[q] = st.y;
    }
  }

  f32x4 acc[4][4];
#pragma unroll
  for (int m = 0; m < 4; ++m)
#pragma unroll
    for (int n = 0; n < 4; ++n) acc[m][n] = (f32x4){0.f, 0.f, 0.f, 0.f};

  for (int kt = 0; kt < K; kt += 64) {
    __syncthreads();                         // prev-tile readers done
#pragma unroll
    for (int q = 0; q < 4; ++q) {            // B: DMA first (overlaps A latency)
      int rl = q * 32 + srow;
      gload_lds16(Bb + (size_t)(tileN + rl) * ldb + kt + sg * 8, &Bs[rl * 64 + sp]);
    }
    if constexpr (EPI == EPI_PVF) {
      const float* Af = (const float*)Ab;    // lda counts f32
#pragma unroll
      for (int q = 0; q < 4; ++q) {
        int rl = q * 32 + srow;
        const float* ap = Af + (size_t)(tileM + rl) * lda + kt + (tid & 7) * 8;
        float4 x0 = *(const float4*)ap;
        float4 x1 = *(const float4*)(ap + 4);
        union { unsigned short h[8]; uint4 u; } pk;
        pk.h[0] = f2bf(__expf(x0.x - mR[q]) * iR[q]);
        pk.h[1] = f2bf(__expf(x0.y - mR[q]) * iR[q]);
        pk.h[2] = f2bf(__expf(x0.z - mR[q]) * iR[q]);
        pk.h[3] = f2bf(__expf(x0.w - mR[q]) * iR[q]);
        pk.h[4] = f2bf(__expf(x1.x - mR[q]) * iR[q]);
        pk.h[5] = f2bf(__expf(x1.y - mR[q]) * iR[q]);
        pk.h[6] = f2bf(__expf(x1.z - mR[q]) * iR[q]);
        pk.h[7] = f2bf(__expf(x1.w - mR[q]) * iR[q]);
        *(uint4*)&As[rl * 64 + (((tid & 7) ^ (rl & 7)) << 3)] = pk.u;  // write-side swizzle
      }
    } else {
#pragma unroll
      for (int q = 0; q < 4; ++q) {
        int rl = q * 32 + srow;
        gload_lds16(Ab + (size_t)(tileM + rl) * lda + kt + sg * 8, &As[rl * 64 + sp]);
      }
    }
    __syncthreads();                         // drain DMA + ds_write (compiler)

    bf16x8 af[4][2], bg[4][2];
#pragma unroll
    for (int m = 0; m < 4; ++m) {
      int row = wr * 64 + m * 16 + fr;
#pragma unroll
      for (int kk = 0; kk < 2; ++kk)
        af[m][kk] = *reinterpret_cast<const bf16x8*>(
            &As[row * 64 + (((kk * 4 + fk) ^ (row & 7)) << 3)]);
    }
#pragma unroll
    for (int n = 0; n < 4; ++n) {
      int row = wc * 64 + n * 16 + fr;
#pragma unroll
      for (int kk = 0; kk < 2; ++kk)
        bg[n][kk] = *reinterpret_cast<const bf16x8*>(
            &Bs[row * 64 + (((kk * 4 + fk) ^ (row & 7)) << 3)]);
    }
#pragma unroll
    for (int kk = 0; kk < 2; ++kk)
#pragma unroll
      for (int m = 0; m < 4; ++m)
#pragma unroll
        for (int n = 0; n < 4; ++n)
          acc[m][n] = __builtin_amdgcn_mfma_f32_16x16x32_bf16(af[m][kk], bg[n][kk], acc[m][n], 0, 0, 0);
  }

  // ---- epilogue ----
  if (EPI == EPI_QKV && tileN >= 2 * DIM) {
    // V tile: write transposed directly into Vt[d][seq] (j is seq-contiguous)
    const int b = tileM >> 11;               // batch
    const int sb0 = (tileM & (SEQ - 1)) + wr * 64;
    unsigned short* Vb = VtOut + (size_t)b * sVt;
#pragma unroll
    for (int m = 0; m < 4; ++m)
#pragma unroll
      for (int n = 0; n < 4; ++n) {
        int col = tileN + wc * 64 + n * 16 + fr;
        int d = col - 2 * DIM;
        int s = sb0 + m * 16 + fk * 4;
        union { unsigned short h[4]; uint2 u; } p;
#pragma unroll
        for (int j = 0; j < 4; ++j) p.h[j] = f2bf(acc[m][n][j] + bias[col]);
        *reinterpret_cast<uint2*>(&Vb[(size_t)d * SEQ + s]) = p.u;
      }
  } else {
#pragma unroll
    for (int m = 0; m < 4; ++m)
#pragma unroll
      for (int n = 0; n < 4; ++n)
#pragma unroll
        for (int j = 0; j < 4; ++j) {
          int row = tileM + wr * 64 + m * 16 + fk * 4 + j;
          int col = tileN + wc * 64 + n * 16 + fr;
          float v = acc[m][n][j];
          if (EPI == EPI_QKV) {
            v += bias[col];
            if (col < DIM) v *= 0.03125f;    // 1/sqrt(1024)
            ((unsigned short*)C + (size_t)blockIdx.z * sC)[(size_t)row * ldc + col] = f2bf(v);
          } else if (EPI == EPI_PVF) {
            ((unsigned short*)C + (size_t)blockIdx.z * sC)[(size_t)row * ldc + col] = f2bf(v);
          } else if (EPI == EPI_BIAS_F32) {
            ((float*)C + (size_t)blockIdx.z * sC)[(size_t)row * ldc + col] = v + bias[col];
          } else {
            ((float*)C + (size_t)blockIdx.z * sC)[(size_t)row * ldc + col] = v;
          }
        }
  }

  // ---- scores stats epilogue (reuses As as f32 scratch) ----
  if constexpr (EPI == EPI_SC) {
    float* sm = (float*)As;        // [2][128]
    float* ss = sm + 256;
    __syncthreads();               // all waves done with LDS (loop complete)
#pragma unroll
    for (int m = 0; m < 4; ++m)
#pragma unroll
      for (int j = 0; j < 4; ++j) {
        float mx = fmaxf(fmaxf(acc[m][0][j], acc[m][1][j]), fmaxf(acc[m][2][j], acc[m][3][j]));
        mx = fmaxf(mx, __shfl_xor(mx, 1));
        mx = fmaxf(mx, __shfl_xor(mx, 2));
        mx = fmaxf(mx, __shfl_xor(mx, 4));
        mx = fmaxf(mx, __shfl_xor(mx, 8));
        float se = __expf(acc[m][0][j] - mx) + __expf(acc[m][1][j] - mx) +
                   __expf(acc[m][2][j] - mx) + __expf(acc[m][3][j] - mx);
        se += __shfl_xor(se, 1);
        se += __shfl_xor(se, 2);
        se += __shfl_xor(se, 4);
        se += __shfl_xor(se, 8);
        if (fr == 0) {
          int r = wr * 64 + m * 16 + fk * 4 + j;
          sm[wc * 128 + r] = mx;
          ss[wc * 128 + r] = se;
        }
      }
    __syncthreads();
    if (tid < 128) {
      float m0 = sm[tid], m1 = sm[128 + tid];
      float s0 = ss[tid], s1 = ss[128 + tid];
      float M = fmaxf(m0, m1);
      float S = s0 * __expf(m0 - M) + s1 * __expf(m1 - M);
      pstat[((size_t)blockIdx.z * NBX + blockIdx.x) * SEQ + tileM + tid] = make_float2(M, S);
    }
  }
}

extern "C" void kernel_launch(void* const* d_in, const int* in_sizes, int n_in,
                              void* d_out, int out_size, void* d_ws, size_t ws_size,
                              hipStream_t stream) {
  const float* X     = (const float*)d_in[0];
  const float* W_in  = (const float*)d_in[1];
  const float* b_in  = (const float*)d_in[2];
  const float* W_out = (const float*)d_in[3];
  const float* b_out = (const float*)d_in[4];
  float* out = (float*)d_out;
  char* ws = (char*)d_ws;

  size_t o = 0;
  auto alloc = [&](size_t bytes) { size_t r = o; o += (bytes + 255) & ~(size_t)255; return r; };
  unsigned short* Xbf   = (unsigned short*)(ws + alloc((size_t)ROWS * DIM * 2));     // aliased as O later
  unsigned short* WinT  = (unsigned short*)(ws + alloc((size_t)3 * DIM * DIM * 2));
  unsigned short* WoutT = (unsigned short*)(ws + alloc((size_t)DIM * DIM * 2));
  unsigned short* QKV   = (unsigned short*)(ws + alloc((size_t)ROWS * 3 * DIM * 2));
  unsigned short* Vt    = (unsigned short*)(ws + alloc((size_t)BATCH * DIM * SEQ * 2)); // QKV fills all batches
  float2*         Pst   = (float2*)(ws + alloc((size_t)BATCH * NBX * SEQ * 8));
  float2*         Rst   = (float2*)(ws + alloc((size_t)BATCH * SEQ * 8));
  size_t fixed = o;
  size_t per_batch = (((size_t)SEQ * SEQ * 4 + 255) & ~(size_t)255);
  int G = (ws_size >= fixed + 4 * per_batch) ? BATCH : 1;
  float* Sc = (float*)(ws + alloc((size_t)G * SEQ * SEQ * 4));
  unsigned short* Ob = Xbf;   // Xbf dead after QKV GEMM

  conv_f32_bf16<<<(ROWS * DIM / 8 + 255) / 256, 256, 0, stream>>>(X, Xbf, ROWS * DIM / 8);
  transpose_weights<<<dim3(32, 32, 4), dim3(32, 32), 0, stream>>>(W_in, WinT, W_out, WoutT);
  // QKV: M-fastest grid (64 M in x, 24 N in y); V transposed directly into Vt
  gemm97<EPI_QKV><<<dim3(ROWS / 128, 3 * DIM / 128, 1), 256, 0, stream>>>(
      Xbf, DIM, 0, WinT, DIM, 0, QKV, 3 * DIM, 0, b_in, DIM,
      Vt, (size_t)DIM * SEQ, nullptr, nullptr);

  for (int b0 = 0; b0 < BATCH; b0 += G) {
    const unsigned short* Qb = QKV + (size_t)b0 * SEQ * 3 * DIM;
    const unsigned short* Kb = Qb + DIM;
    // scores + per-tile stats: grid (16,16,G)
    gemm97<EPI_SC><<<dim3(SEQ / 128, SEQ / 128, G), 256, 0, stream>>>(
        Qb, 3 * DIM, (size_t)SEQ * 3 * DIM, Kb, 3 * DIM, (size_t)SEQ * 3 * DIM,
        Sc, SEQ, (size_t)SEQ * SEQ, nullptr, DIM, nullptr, 0,
        Pst + (size_t)b0 * NBX * SEQ, nullptr);
    // combine stats -> (rowmax, 1/rowsum)
    stat_combine<<<dim3(SEQ / 256, G), 256, 0, stream>>>(
        Pst + (size_t)b0 * NBX * SEQ, Rst + (size_t)b0 * SEQ);
    // fused-exp PV: grid (8,16,G); A = raw S f32 (lda in f32), sA in shorts
    gemm97<EPI_PVF><<<dim3(DIM / 128, SEQ / 128, G), 256, 0, stream>>>(
        (const unsigned short*)Sc, SEQ, (size_t)2 * SEQ * SEQ,
        Vt + (size_t)b0 * DIM * SEQ, SEQ, (size_t)DIM * SEQ,
        Ob + (size_t)b0 * SEQ * DIM, DIM, (size_t)SEQ * DIM, nullptr, SEQ,
        nullptr, 0, nullptr, Rst + (size_t)b0 * SEQ);
  }
  // proj: grid (8,64)
  gemm97<EPI_BIAS_F32><<<dim3(DIM / 128, ROWS / 128, 1), 256, 0, stream>>>(
      Ob, DIM, 0, WoutT, DIM, 0, out, DIM, 0, b_out, DIM, nullptr, 0, nullptr, nullptr);
}

// Round 15
// 204.137 us; speedup vs baseline: 1.1627x; 1.1627x over previous
//
#include <hip/hip_runtime.h>
#include <hip/hip_bf16.h>
#include <math.h>

typedef __attribute__((ext_vector_type(8))) __bf16 bf16x8;
typedef __attribute__((ext_vector_type(4))) float f32x4;

#define DIM 1024
#define SEQ 2048
#define BATCH 4
#define ROWS (BATCH*SEQ)

__device__ __forceinline__ unsigned short f2bf(float f) {
  unsigned int u = __float_as_uint(f);
  u += 0x7FFF + ((u >> 16) & 1);   // RNE
  return (unsigned short)(u >> 16);
}

__device__ __forceinline__ void gload_lds16(const void* g, void* lds) {
  __builtin_amdgcn_global_load_lds((__attribute__((address_space(1))) void*)g,
                                   (__attribute__((address_space(3))) void*)lds,
                                   16, 0, 0);
}

// ---------- f32 -> bf16 ----------
__global__ __launch_bounds__(256)
void conv_f32_bf16(const float* __restrict__ src, unsigned short* __restrict__ dst, int n8) {
  int i = blockIdx.x * blockDim.x + threadIdx.x;
  if (i >= n8) return;
  const float4* s = reinterpret_cast<const float4*>(src) + (size_t)i * 2;
  float4 a = s[0], b = s[1];
  union { unsigned short h[8]; uint4 v; } p;
  p.h[0]=f2bf(a.x); p.h[1]=f2bf(a.y); p.h[2]=f2bf(a.z); p.h[3]=f2bf(a.w);
  p.h[4]=f2bf(b.x); p.h[5]=f2bf(b.y); p.h[6]=f2bf(b.z); p.h[7]=f2bf(b.w);
  reinterpret_cast<uint4*>(dst)[i] = p.v;
}

// ---------- merged weight transpose: z=0..2 -> W_in col-chunks, z=3 -> W_out ----------
__global__ __launch_bounds__(1024)
void transpose_weights(const float* __restrict__ W_in, unsigned short* __restrict__ WinT,
                       const float* __restrict__ W_out, unsigned short* __restrict__ WoutT) {
  __shared__ unsigned short tile[32][33];
  const int z = blockIdx.z;
  const float* src; unsigned short* dst; int ldsrc, bx;
  if (z < 3) { src = W_in;  dst = WinT;  ldsrc = 3 * DIM; bx = z * 32 + blockIdx.x; }
  else       { src = W_out; dst = WoutT; ldsrc = DIM;     bx = blockIdx.x; }
  int tx = threadIdx.x, ty = threadIdx.y;
  int r = blockIdx.y * 32 + ty, c = bx * 32 + tx;
  tile[ty][tx] = f2bf(src[(size_t)r * ldsrc + c]);
  __syncthreads();
  dst[(size_t)(bx * 32 + ty) * DIM + blockIdx.y * 32 + tx] = tile[tx][ty];
}

#define EPI_QKV 0
#define EPI_F32 1
#define EPI_BF16 2
#define EPI_BIAS_F32 3

// ---------- m97-archetype NT GEMM: C[M,N] = A[M,K]*B[N,K]^T ----------
// 128x128 tile, BK=64, 4 waves (2x2), per-wave 64x64, 32 KB LDS single-buffer.
// 2 barriers per K-tile; compiler-scheduled ds_reads; ~3 blocks/CU hide the
// vmcnt(0) drain (measured: QKV 799 TF in this structure, r12).
// XOR swizzle (source pre-swizzle + read XOR) for 0-conflict ds_read_b128.
// EPI_QKV: M-fastest grid order (B-panel L2 reuse; FETCH 72.8->41.5 MB, r13)
// and V-column tiles (tileN>=2*DIM) write transposed directly to Vt.
template<int EPI>
__global__ __launch_bounds__(256, 3)
void gemm97(const unsigned short* __restrict__ A, int lda, size_t sA,
            const unsigned short* __restrict__ B, int ldb, size_t sB,
            void* __restrict__ C, int ldc, size_t sC,
            const float* __restrict__ bias, int K,
            unsigned short* __restrict__ VtOut, size_t sVt) {
  __shared__ unsigned short As[128 * 64];
  __shared__ unsigned short Bs[128 * 64];

  const int tid = threadIdx.x;
  const int lane = tid & 63, wave = tid >> 6;
  const int wr = wave >> 1, wc = wave & 1;
  const int fr = lane & 15, fk = lane >> 4;
  // M-fastest for QKV (B-panel L2 reuse); N-fastest otherwise.
  const int tileM = (EPI == EPI_QKV ? blockIdx.x : blockIdx.y) * 128;
  const int tileN = (EPI == EPI_QKV ? blockIdx.y : blockIdx.x) * 128;
  const unsigned short* Ab = A + (size_t)blockIdx.z * sA;
  const unsigned short* Bb = B + (size_t)blockIdx.z * sB;

  // staging: 256 thr x 16B = 4 KB/round = 32 rows of 128B; 4 rounds per tile.
  const int srow = tid >> 3;                 // 0..31
  const int sg = (tid & 7) ^ (srow & 7);     // pre-swizzled source 16B-chunk
  const int sp = (tid & 7) * 8;              // linear LDS slot (shorts)

  f32x4 acc[4][4];
#pragma unroll
  for (int m = 0; m < 4; ++m)
#pragma unroll
    for (int n = 0; n < 4; ++n) acc[m][n] = (f32x4){0.f, 0.f, 0.f, 0.f};

  for (int kt = 0; kt < K; kt += 64) {
    __syncthreads();                         // prev-tile readers done
#pragma unroll
    for (int q = 0; q < 4; ++q) {
      int rl = q * 32 + srow;
      gload_lds16(Ab + (size_t)(tileM + rl) * lda + kt + sg * 8, &As[rl * 64 + sp]);
    }
#pragma unroll
    for (int q = 0; q < 4; ++q) {
      int rl = q * 32 + srow;
      gload_lds16(Bb + (size_t)(tileN + rl) * ldb + kt + sg * 8, &Bs[rl * 64 + sp]);
    }
    __syncthreads();                         // vmcnt(0) drain (compiler-inserted)

    bf16x8 af[4][2], bg[4][2];
#pragma unroll
    for (int m = 0; m < 4; ++m) {
      int row = wr * 64 + m * 16 + fr;
#pragma unroll
      for (int kk = 0; kk < 2; ++kk)
        af[m][kk] = *reinterpret_cast<const bf16x8*>(
            &As[row * 64 + (((kk * 4 + fk) ^ (row & 7)) << 3)]);
    }
#pragma unroll
    for (int n = 0; n < 4; ++n) {
      int row = wc * 64 + n * 16 + fr;
#pragma unroll
      for (int kk = 0; kk < 2; ++kk)
        bg[n][kk] = *reinterpret_cast<const bf16x8*>(
            &Bs[row * 64 + (((kk * 4 + fk) ^ (row & 7)) << 3)]);
    }
#pragma unroll
    for (int kk = 0; kk < 2; ++kk)
#pragma unroll
      for (int m = 0; m < 4; ++m)
#pragma unroll
        for (int n = 0; n < 4; ++n)
          acc[m][n] = __builtin_amdgcn_mfma_f32_16x16x32_bf16(af[m][kk], bg[n][kk], acc[m][n], 0, 0, 0);
  }

  // ---- epilogue ----
  if (EPI == EPI_QKV && tileN >= 2 * DIM) {
    // V tile: write transposed directly into Vt[d][seq] (j is seq-contiguous)
    const int b = tileM >> 11;               // batch
    const int sb0 = (tileM & (SEQ - 1)) + wr * 64;
    unsigned short* Vb = VtOut + (size_t)b * sVt;
#pragma unroll
    for (int m = 0; m < 4; ++m)
#pragma unroll
      for (int n = 0; n < 4; ++n) {
        int col = tileN + wc * 64 + n * 16 + fr;
        int d = col - 2 * DIM;
        int s = sb0 + m * 16 + fk * 4;
        union { unsigned short h[4]; uint2 u; } p;
#pragma unroll
        for (int j = 0; j < 4; ++j) p.h[j] = f2bf(acc[m][n][j] + bias[col]);
        *reinterpret_cast<uint2*>(&Vb[(size_t)d * SEQ + s]) = p.u;
      }
  } else {
#pragma unroll
    for (int m = 0; m < 4; ++m)
#pragma unroll
      for (int n = 0; n < 4; ++n)
#pragma unroll
        for (int j = 0; j < 4; ++j) {
          int row = tileM + wr * 64 + m * 16 + fk * 4 + j;
          int col = tileN + wc * 64 + n * 16 + fr;
          float v = acc[m][n][j];
          if (EPI == EPI_QKV) {
            v += bias[col];
            if (col < DIM) v *= 0.03125f;    // 1/sqrt(1024)
            ((unsigned short*)C + (size_t)blockIdx.z * sC)[(size_t)row * ldc + col] = f2bf(v);
          } else if (EPI == EPI_BF16) {
            ((unsigned short*)C + (size_t)blockIdx.z * sC)[(size_t)row * ldc + col] = f2bf(v);
          } else if (EPI == EPI_BIAS_F32) {
            ((float*)C + (size_t)blockIdx.z * sC)[(size_t)row * ldc + col] = v + bias[col];
          } else {
            ((float*)C + (size_t)blockIdx.z * sC)[(size_t)row * ldc + col] = v;
          }
        }
  }
}

// ---------- row softmax, in-place: fp32 row -> bf16 P at row start ----------
__global__ __launch_bounds__(256)
void softmax_kernel(float* __restrict__ S, size_t zstride) {
  __shared__ float red[8];
  float* row = S + (size_t)blockIdx.y * zstride + (size_t)blockIdx.x * SEQ;
  const int tid = threadIdx.x;
  const int lane = tid & 63, wave = tid >> 6;
  const float4* src = reinterpret_cast<const float4*>(row) + tid * 2;
  float4 a = src[0], b = src[1];
  float v[8] = {a.x, a.y, a.z, a.w, b.x, b.y, b.z, b.w};
  float m = v[0];
#pragma unroll
  for (int i = 1; i < 8; ++i) m = fmaxf(m, v[i]);
  for (int o = 32; o; o >>= 1) m = fmaxf(m, __shfl_xor(m, o));
  if (lane == 0) red[wave] = m;
  __syncthreads();
  m = fmaxf(fmaxf(red[0], red[1]), fmaxf(red[2], red[3]));
  float e[8], s = 0.f;
#pragma unroll
  for (int i = 0; i < 8; ++i) { e[i] = __expf(v[i] - m); s += e[i]; }
  for (int o = 32; o; o >>= 1) s += __shfl_xor(s, o);
  if (lane == 0) red[4 + wave] = s;
  __syncthreads();
  s = red[4] + red[5] + red[6] + red[7];
  float inv = 1.f / s;
  union { unsigned short h[8]; uint4 u; } p;
#pragma unroll
  for (int i = 0; i < 8; ++i) p.h[i] = f2bf(e[i] * inv);
  reinterpret_cast<uint4*>(row)[tid] = p.u;
}

extern "C" void kernel_launch(void* const* d_in, const int* in_sizes, int n_in,
                              void* d_out, int out_size, void* d_ws, size_t ws_size,
                              hipStream_t stream) {
  const float* X     = (const float*)d_in[0];
  const float* W_in  = (const float*)d_in[1];
  const float* b_in  = (const float*)d_in[2];
  const float* W_out = (const float*)d_in[3];
  const float* b_out = (const float*)d_in[4];
  float* out = (float*)d_out;
  char* ws = (char*)d_ws;

  size_t o = 0;
  auto alloc = [&](size_t bytes) { size_t r = o; o += (bytes + 255) & ~(size_t)255; return r; };
  unsigned short* Xbf   = (unsigned short*)(ws + alloc((size_t)ROWS * DIM * 2));     // aliased as O later
  unsigned short* WinT  = (unsigned short*)(ws + alloc((size_t)3 * DIM * DIM * 2));
  unsigned short* WoutT = (unsigned short*)(ws + alloc((size_t)DIM * DIM * 2));
  unsigned short* QKV   = (unsigned short*)(ws + alloc((size_t)ROWS * 3 * DIM * 2));
  unsigned short* Vt    = (unsigned short*)(ws + alloc((size_t)BATCH * DIM * SEQ * 2)); // QKV fills all batches
  size_t fixed = o;
  size_t per_batch = (((size_t)SEQ * SEQ * 4 + 255) & ~(size_t)255);
  int G = (ws_size >= fixed + 4 * per_batch) ? BATCH : 1;
  float* Sc = (float*)(ws + alloc((size_t)G * SEQ * SEQ * 4));  // P written in place (bf16)
  unsigned short* Ob = Xbf;   // Xbf dead after QKV GEMM

  conv_f32_bf16<<<(ROWS * DIM / 8 + 255) / 256, 256, 0, stream>>>(X, Xbf, ROWS * DIM / 8);
  transpose_weights<<<dim3(32, 32, 4), dim3(32, 32), 0, stream>>>(W_in, WinT, W_out, WoutT);
  // QKV: M-fastest grid (64 M-blocks in x, 24 N-blocks in y) = 1536 blocks
  gemm97<EPI_QKV><<<dim3(ROWS / 128, 3 * DIM / 128, 1), 256, 0, stream>>>(
      Xbf, DIM, 0, WinT, DIM, 0, QKV, 3 * DIM, 0, b_in, DIM,
      Vt, (size_t)DIM * SEQ);

  for (int b0 = 0; b0 < BATCH; b0 += G) {
    const unsigned short* Qb = QKV + (size_t)b0 * SEQ * 3 * DIM;
    const unsigned short* Kb = Qb + DIM;
    // scores: grid (16,16,G) = 1024 blocks
    gemm97<EPI_F32><<<dim3(SEQ / 128, SEQ / 128, G), 256, 0, stream>>>(
        Qb, 3 * DIM, (size_t)SEQ * 3 * DIM, Kb, 3 * DIM, (size_t)SEQ * 3 * DIM,
        Sc, SEQ, (size_t)SEQ * SEQ, nullptr, DIM, nullptr, 0);
    softmax_kernel<<<dim3(SEQ, G), 256, 0, stream>>>(Sc, (size_t)SEQ * SEQ);
    // PV: grid (8,16,G) = 512 blocks
    gemm97<EPI_BF16><<<dim3(DIM / 128, SEQ / 128, G), 256, 0, stream>>>(
        (const unsigned short*)Sc, 2 * SEQ, (size_t)2 * SEQ * SEQ,
        Vt + (size_t)b0 * DIM * SEQ, SEQ, (size_t)DIM * SEQ,
        Ob + (size_t)b0 * SEQ * DIM, DIM, (size_t)SEQ * DIM, nullptr, SEQ, nullptr, 0);
  }
  // proj: grid (8,64) = 512 blocks
  gemm97<EPI_BIAS_F32><<<dim3(DIM / 128, ROWS / 128, 1), 256, 0, stream>>>(
      Ob, DIM, 0, WoutT, DIM, 0, out, DIM, 0, b_out, DIM, nullptr, 0);
}